// Round 7
// baseline (123.821 us; speedup 1.0000x reference)
//
#include <hip/hip_runtime.h>
#include <hip/hip_bf16.h>

#define FDIM 256
#define K2   512
#define DNB  32
#define TM   32
#define TMAX 20480

typedef __attribute__((ext_vector_type(8))) short bf16x8;
typedef __attribute__((ext_vector_type(4))) float f32x4;

// Device-global scratch & precomputed weights (fully rewritten every launch).
__device__ __align__(16) unsigned short g_X[(size_t)TMAX * K2];  // bf16 gathered rows
__device__ float g_Sdeg[TMAX];
__device__ __align__(16) unsigned short g_Wc[FDIM * K2];         // [o][k] bf16
__device__ float g_c2[FDIM];
__device__ float g_c3[FDIM];

__device__ __forceinline__ unsigned short f2bf(float f) {
    __hip_bfloat16 h = __float2bfloat16(f);
    return *reinterpret_cast<unsigned short*>(&h);
}
__device__ __forceinline__ ushort4 cvt4(float x, float y, float z, float w) {
    return make_ushort4(f2bf(x), f2bf(y), f2bf(z), f2bf(w));
}

// ---------- 1) prep_gather ----------
// blocks [0,256): weight combine + c2/c3   (o = bid)
// blocks [256,...): gather, 1 wave per node, fp32 feat_data direct
__global__ __launch_bounds__(256, 6) void prep_gather(
    const float* __restrict__ fd,
    const float* __restrict__ feats,
    const float* __restrict__ W1,
    const float* __restrict__ W2,
    const float* __restrict__ b1,
    const float* __restrict__ b2,
    float Dmul,
    const int* __restrict__ adj,
    const int* __restrict__ in1, int B1,
    const int* __restrict__ in2, int B2,
    const int* __restrict__ neg, int total)
{
    int bid = blockIdx.x;
    int tid = threadIdx.x;

    if (bid < 256) {
        // ---- weight combine: 256 threads, each handles k0=tid, k1=tid+256
        __shared__ float w2s[FDIM];
        __shared__ float rv[4], ru[4];
        int o = bid;
        w2s[tid] = W2[(size_t)o * K2 + FDIM + tid];
        __syncthreads();

        const float* w1a = W1 + tid;           // column k0
        const float* w1b = W1 + FDIM + tid;    // column k1
        float acc0 = 0.f, acc1 = 0.f;
        for (int j = 0; j < FDIM; j += 8) {
            float r0[8], r1[8];
            #pragma unroll
            for (int u = 0; u < 8; ++u) {
                r0[u] = w1a[(size_t)(j + u) * K2];
                r1[u] = w1b[(size_t)(j + u) * K2];
            }
            #pragma unroll
            for (int u = 0; u < 8; ++u) {
                acc0 = fmaf(w2s[j + u], r0[u], acc0);
                acc1 = fmaf(w2s[j + u], r1[u], acc1);
            }
        }
        // C1 half (k0 < 256) and W2a half
        g_Wc[(size_t)o * K2 + FDIM + tid] = f2bf(acc0);
        g_Wc[(size_t)o * K2 + tid]        = f2bf(W2[(size_t)o * K2 + tid]);

        float v = acc1;                        // c2[o] = sum over k1 of acc1
        float u = b1[tid] * w2s[tid];          // c3 dot
        #pragma unroll
        for (int s = 32; s; s >>= 1) { v += __shfl_down(v, s); u += __shfl_down(u, s); }
        if ((tid & 63) == 0) { rv[tid >> 6] = v; ru[tid >> 6] = u; }
        __syncthreads();
        if (tid == 0) {
            float sv = rv[0] + rv[1] + rv[2] + rv[3];
            float su = ru[0] + ru[1] + ru[2] + ru[3];
            g_c2[o] = sv;
            g_c3[o] = b2[o] + Dmul * su;
        }
        return;
    }

    // ---- gather: t = node slot, one wave per node
    int wave = tid >> 6, lane = tid & 63;
    int t = (bid - 256) * 4 + wave;
    if (t >= total) return;
    int node = (t < B1) ? in1[t] : ((t < B1 + B2) ? in2[t - B1] : neg[t - B1 - B2]);

    const float4* fd4 = (const float4*)fd;

    int idx = 0; float deg = 0.f;
    if (lane < DNB) {
        idx = adj[(size_t)node * DNB + lane];
        deg = feats[(size_t)idx * FDIM];       // scattered 4B, hidden under row loads
    }
    #pragma unroll
    for (int s = 16; s; s >>= 1) deg += __shfl_down(deg, s);
    if (lane == 0) g_Sdeg[t] = deg;

    // node row: one full 1KB wave-load
    float4 nf = fd4[(size_t)node * 64 + lane];

    // neighbor sum: 8 full rows (8KB) in flight per step, two dep chains
    float4 a0 = make_float4(0.f, 0.f, 0.f, 0.f), a1 = a0;
    #pragma unroll
    for (int d = 0; d < DNB; d += 8) {
        float4 v[8];
        #pragma unroll
        for (int u = 0; u < 8; ++u) {
            int nb = __shfl(idx, d + u);
            v[u] = fd4[(size_t)nb * 64 + lane];
        }
        #pragma unroll
        for (int u = 0; u < 8; u += 2) {
            a0.x += v[u].x;     a0.y += v[u].y;     a0.z += v[u].z;     a0.w += v[u].w;
            a1.x += v[u + 1].x; a1.y += v[u + 1].y; a1.z += v[u + 1].z; a1.w += v[u + 1].w;
        }
    }
    float ax = a0.x + a1.x, ay = a0.y + a1.y, az = a0.z + a1.z, aw = a0.w + a1.w;

    *(ushort4*)(g_X + (size_t)t * K2 + lane * 4)        = cvt4(nf.x, nf.y, nf.z, nf.w);
    *(ushort4*)(g_X + (size_t)t * K2 + FDIM + lane * 4) = cvt4(ax, ay, az, aw);
}

// ---------- 2) GEMM (MFMA) + degree term + L2 normalize ----------
__global__ __launch_bounds__(256, 4) void gemm_norm(float* __restrict__ out, int total)
{
    __shared__ __align__(16) char lds[TM * 1024];  // bf16 [32][512]; reused f32 [32][256]
    __shared__ float Sdeg[TM];

    int tid = threadIdx.x, wave = tid >> 6, lane = tid & 63;
    int base = blockIdx.x * TM;

    if (tid < TM) {
        int t = base + tid;
        Sdeg[tid] = (t < total) ? g_Sdeg[t] : 0.f;
    }
    // stage X rows (coalesced 16B/lane), swizzled LDS writes
    #pragma unroll
    for (int i = 0; i < 8; ++i) {
        int row = wave * 8 + i;
        int t = base + row;
        bf16x8 v = {0, 0, 0, 0, 0, 0, 0, 0};
        if (t < total) v = *(const bf16x8*)(g_X + (size_t)t * K2 + lane * 8);
        *(bf16x8*)(lds + row * 1024 + ((lane * 16) ^ ((row & 7) << 4))) = v;
    }
    __syncthreads();

    // MFMA: wave w -> cols w*64 (4 tiles of 16), rows 0..31 (2 tiles)
    int l15 = lane & 15, lg = lane >> 4;
    int swzA = (l15 & 7) << 4;
    f32x4 acc[2][4];
    #pragma unroll
    for (int mt = 0; mt < 2; ++mt)
        #pragma unroll
        for (int nt = 0; nt < 4; ++nt) acc[mt][nt] = (f32x4){0.f, 0.f, 0.f, 0.f};

    const char* pA0 = lds + (size_t)l15 * 1024;
    const char* pA1 = lds + (size_t)(16 + l15) * 1024;
    const unsigned short* wcB = g_Wc + (size_t)(wave * 64 + l15) * K2 + lg * 8;

    #pragma unroll 4
    for (int kk = 0; kk < K2; kk += 32) {
        int kb = kk * 2 + lg * 16;
        bf16x8 a0 = *(const bf16x8*)(pA0 + (kb ^ swzA));
        bf16x8 a1 = *(const bf16x8*)(pA1 + (kb ^ swzA));
        #pragma unroll
        for (int nt = 0; nt < 4; ++nt) {
            bf16x8 b = *(const bf16x8*)(wcB + (size_t)nt * 16 * K2 + kk);
            acc[0][nt] = __builtin_amdgcn_mfma_f32_16x16x32_bf16(a0, b, acc[0][nt], 0, 0, 0);
            acc[1][nt] = __builtin_amdgcn_mfma_f32_16x16x32_bf16(a1, b, acc[1][nt], 0, 0, 0);
        }
    }
    __syncthreads();

    // stage raw acc to LDS as f32 [32][256] (HW-verified D layout)
    float* outf = (float*)lds;
    #pragma unroll
    for (int mt = 0; mt < 2; ++mt)
        #pragma unroll
        for (int nt = 0; nt < 4; ++nt)
            #pragma unroll
            for (int r = 0; r < 4; ++r) {
                int row = mt * 16 + lg * 4 + r;
                int col = wave * 64 + nt * 16 + l15;
                outf[row * 256 + col] = acc[mt][nt][r];
            }
    __syncthreads();

    // epilogue: v = acc + Sdeg*c2 + c3 (fp32), L2-normalize, store
    float4 c2v = *(const float4*)(g_c2 + lane * 4);
    float4 c3v = *(const float4*)(g_c3 + lane * 4);
    for (int r = 0; r < 8; ++r) {
        int row = wave * 8 + r;
        int t = base + row;
        if (t >= total) break;                   // wave-uniform
        float sd = Sdeg[row];
        float4 v = *(float4*)(outf + row * 256 + lane * 4);
        v.x += sd * c2v.x + c3v.x;
        v.y += sd * c2v.y + c3v.y;
        v.z += sd * c2v.z + c3v.z;
        v.w += sd * c2v.w + c3v.w;
        float ss = v.x * v.x + v.y * v.y + v.z * v.z + v.w * v.w;
        #pragma unroll
        for (int s = 32; s; s >>= 1) ss += __shfl_xor(ss, s);
        float inv = 1.0f / fmaxf(sqrtf(ss), 1e-12f);
        v.x *= inv; v.y *= inv; v.z *= inv; v.w *= inv;
        *(float4*)(out + (size_t)t * FDIM + lane * 4) = v;
    }
}

extern "C" void kernel_launch(void* const* d_in, const int* in_sizes, int n_in,
                              void* d_out, int out_size, void* d_ws, size_t ws_size,
                              hipStream_t stream) {
    const float* feat_data = (const float*)d_in[0];
    const float* feats     = (const float*)d_in[1];
    const float* W1        = (const float*)d_in[2];
    const float* b1        = (const float*)d_in[3];
    const float* W2        = (const float*)d_in[4];
    const float* b2        = (const float*)d_in[5];
    const int*   adj       = (const int*)d_in[6];
    const int*   in1       = (const int*)d_in[7];
    const int*   in2       = (const int*)d_in[8];
    const int*   neg       = (const int*)d_in[9];

    int B1 = in_sizes[7];
    int B2 = in_sizes[8];
    int Bn = in_sizes[9];
    int N  = in_sizes[0] / FDIM;
    int D  = in_sizes[6] / N;   // == 32

    float* out = (float*)d_out;
    int total = B1 + B2 + Bn;

    int gatherBlocks = (total + 3) / 4;
    prep_gather<<<256 + gatherBlocks, 256, 0, stream>>>(
        feat_data, feats, W1, W2, b1, b2, (float)D,
        adj, in1, B1, in2, B2, neg, total);
    gemm_norm<<<(total + TM - 1) / TM, 256, 0, stream>>>(out, total);
}

// Round 8
// 112.592 us; speedup vs baseline: 1.0997x; 1.0997x over previous
//
#include <hip/hip_runtime.h>
#include <hip/hip_bf16.h>

#define FDIM 256
#define K2   512
#define DNB  32
#define TM   32
#define NMAX 100000
#define TMAX 20480

typedef __attribute__((ext_vector_type(8))) short bf16x8;
typedef __attribute__((ext_vector_type(4))) float f32x4;

// Fallback scratch in BSS (used only if ws_size is too small).
__device__ __align__(16) unsigned short g_FDb[(size_t)NMAX * FDIM];
__device__ __align__(16) unsigned short g_Xb[(size_t)TMAX * K2];
__device__ float g_degb[NMAX];
__device__ float g_Sdegb[TMAX];
// Small combined-weight arrays stay in BSS (256 KB total, read-heavy).
__device__ __align__(16) unsigned short g_Wc[FDIM * K2];   // [o][k] bf16
__device__ float g_c2[FDIM];
__device__ float g_c3[FDIM];

__device__ __forceinline__ unsigned short f2bf(float f) {
    __hip_bfloat16 h = __float2bfloat16(f);
    return *reinterpret_cast<unsigned short*>(&h);
}
__device__ __forceinline__ float bf2f(unsigned short u) {
    return __uint_as_float(((unsigned)u) << 16);
}
__device__ __forceinline__ ushort4 cvt4(float4 v) {
    return make_ushort4(f2bf(v.x), f2bf(v.y), f2bf(v.z), f2bf(v.w));
}

// ---------- 1) build: fp32 feat_data -> bf16 table (in ws) + degree table ----------
__global__ __launch_bounds__(256) void build(const float* __restrict__ fd,
                                             const float* __restrict__ feats,
                                             unsigned short* tab_p, float* deg_p,
                                             int N) {
    unsigned short* tab = tab_p ? tab_p : g_FDb;
    float* deg = deg_p ? deg_p : g_degb;

    size_t tidg = (size_t)blockIdx.x * 256 + threadIdx.x;
    size_t nthr = (size_t)gridDim.x * 256;
    size_t total4 = (size_t)N * (FDIM / 4);
    const float4* in4 = (const float4*)fd;
    ushort4* out4 = (ushort4*)tab;

    size_t i = tidg;
    for (; i + 3 * nthr < total4; i += 4 * nthr) {
        float4 a0 = in4[i];
        float4 a1 = in4[i + nthr];
        float4 a2 = in4[i + 2 * nthr];
        float4 a3 = in4[i + 3 * nthr];
        out4[i]            = cvt4(a0);
        out4[i + nthr]     = cvt4(a1);
        out4[i + 2 * nthr] = cvt4(a2);
        out4[i + 3 * nthr] = cvt4(a3);
    }
    for (; i < total4; i += nthr)
        out4[i] = cvt4(in4[i]);

    for (size_t n = tidg; n < (size_t)N; n += nthr)
        deg[n] = feats[n * FDIM];
}

// ---------- 2) prep_w: combined weights (R7-validated logic) ----------
__global__ __launch_bounds__(256) void prep_w(const float* __restrict__ W1,
                                              const float* __restrict__ W2,
                                              const float* __restrict__ b1,
                                              const float* __restrict__ b2,
                                              float Dmul) {
    __shared__ float w2s[FDIM];
    __shared__ float rv[4], ru[4];
    int o = blockIdx.x, tid = threadIdx.x;
    w2s[tid] = W2[(size_t)o * K2 + FDIM + tid];
    __syncthreads();

    const float* w1a = W1 + tid;           // column k0 = tid       -> C1
    const float* w1b = W1 + FDIM + tid;    // column k1 = 256+tid   -> c2 sum
    float acc0 = 0.f, acc1 = 0.f;
    for (int j = 0; j < FDIM; j += 8) {
        float r0[8], r1[8];
        #pragma unroll
        for (int u = 0; u < 8; ++u) {
            r0[u] = w1a[(size_t)(j + u) * K2];
            r1[u] = w1b[(size_t)(j + u) * K2];
        }
        #pragma unroll
        for (int u = 0; u < 8; ++u) {
            acc0 = fmaf(w2s[j + u], r0[u], acc0);
            acc1 = fmaf(w2s[j + u], r1[u], acc1);
        }
    }
    g_Wc[(size_t)o * K2 + FDIM + tid] = f2bf(acc0);
    g_Wc[(size_t)o * K2 + tid]        = f2bf(W2[(size_t)o * K2 + tid]);

    float v = acc1;
    float u = b1[tid] * w2s[tid];
    #pragma unroll
    for (int s = 32; s; s >>= 1) { v += __shfl_down(v, s); u += __shfl_down(u, s); }
    if ((tid & 63) == 0) { rv[tid >> 6] = v; ru[tid >> 6] = u; }
    __syncthreads();
    if (tid == 0) {
        g_c2[o] = rv[0] + rv[1] + rv[2] + rv[3];
        g_c3[o] = b2[o] + Dmul * (ru[0] + ru[1] + ru[2] + ru[3]);
    }
}

// ---------- 3) gather: bf16 table rows, 1 wave/node, 8 rows in flight ----------
__global__ __launch_bounds__(256, 6) void gather(
    const unsigned short* tab_p, const float* deg_p,
    const int* __restrict__ adj,
    const int* __restrict__ in1, int B1,
    const int* __restrict__ in2, int B2,
    const int* __restrict__ neg, int total,
    unsigned short* X_p, float* Sdeg_p)
{
    const unsigned short* tab = tab_p ? tab_p : g_FDb;
    const float* deg = deg_p ? deg_p : g_degb;
    unsigned short* X = X_p ? X_p : g_Xb;
    float* Sdeg = Sdeg_p ? Sdeg_p : g_Sdegb;

    int wave = threadIdx.x >> 6, lane = threadIdx.x & 63;
    int t = blockIdx.x * 4 + wave;
    if (t >= total) return;
    int node = (t < B1) ? in1[t] : ((t < B1 + B2) ? in2[t - B1] : neg[t - B1 - B2]);

    int idx = 0; float dg = 0.f;
    if (lane < DNB) {
        idx = adj[(size_t)node * DNB + lane];
        dg = deg[idx];
    }
    #pragma unroll
    for (int s = 16; s; s >>= 1) dg += __shfl_down(dg, s);
    if (lane == 0) Sdeg[t] = dg;

    // node row passthrough (bf16): 8B/lane = full 512B row per wave-load
    ushort4 nf = *(const ushort4*)(tab + (size_t)node * FDIM + lane * 4);
    *(ushort4*)(X + (size_t)t * K2 + lane * 4) = nf;

    float a0 = 0.f, a1 = 0.f, a2 = 0.f, a3 = 0.f;
    #pragma unroll
    for (int d = 0; d < DNB; d += 8) {
        ushort4 v[8];
        #pragma unroll
        for (int u = 0; u < 8; ++u) {
            int nb = __shfl(idx, d + u);
            v[u] = *(const ushort4*)(tab + (size_t)nb * FDIM + lane * 4);
        }
        #pragma unroll
        for (int u = 0; u < 8; ++u) {
            a0 += bf2f(v[u].x);
            a1 += bf2f(v[u].y);
            a2 += bf2f(v[u].z);
            a3 += bf2f(v[u].w);
        }
    }
    *(ushort4*)(X + (size_t)t * K2 + FDIM + lane * 4) =
        make_ushort4(f2bf(a0), f2bf(a1), f2bf(a2), f2bf(a3));
}

// ---------- 4) GEMM (MFMA) + degree term + L2 normalize ----------
__global__ __launch_bounds__(256, 4) void gemm_norm(const unsigned short* X_p,
                                                    const float* Sdeg_p,
                                                    float* __restrict__ out, int total)
{
    const unsigned short* X = X_p ? X_p : g_Xb;
    const float* SdegG = Sdeg_p ? Sdeg_p : g_Sdegb;

    __shared__ __align__(16) char lds[TM * 1024];  // bf16 [32][512]; reused f32 [32][256]
    __shared__ float Sdeg[TM];

    int tid = threadIdx.x, wave = tid >> 6, lane = tid & 63;
    int base = blockIdx.x * TM;

    if (tid < TM) {
        int t = base + tid;
        Sdeg[tid] = (t < total) ? SdegG[t] : 0.f;
    }
    #pragma unroll
    for (int i = 0; i < 8; ++i) {
        int row = wave * 8 + i;
        int t = base + row;
        bf16x8 v = {0, 0, 0, 0, 0, 0, 0, 0};
        if (t < total) v = *(const bf16x8*)(X + (size_t)t * K2 + lane * 8);
        *(bf16x8*)(lds + row * 1024 + ((lane * 16) ^ ((row & 7) << 4))) = v;
    }
    __syncthreads();

    int l15 = lane & 15, lg = lane >> 4;
    int swzA = (l15 & 7) << 4;
    f32x4 acc[2][4];
    #pragma unroll
    for (int mt = 0; mt < 2; ++mt)
        #pragma unroll
        for (int nt = 0; nt < 4; ++nt) acc[mt][nt] = (f32x4){0.f, 0.f, 0.f, 0.f};

    const char* pA0 = lds + (size_t)l15 * 1024;
    const char* pA1 = lds + (size_t)(16 + l15) * 1024;
    const unsigned short* wcB = g_Wc + (size_t)(wave * 64 + l15) * K2 + lg * 8;

    #pragma unroll 4
    for (int kk = 0; kk < K2; kk += 32) {
        int kb = kk * 2 + lg * 16;
        bf16x8 a0 = *(const bf16x8*)(pA0 + (kb ^ swzA));
        bf16x8 a1 = *(const bf16x8*)(pA1 + (kb ^ swzA));
        #pragma unroll
        for (int nt = 0; nt < 4; ++nt) {
            bf16x8 b = *(const bf16x8*)(wcB + (size_t)nt * 16 * K2 + kk);
            acc[0][nt] = __builtin_amdgcn_mfma_f32_16x16x32_bf16(a0, b, acc[0][nt], 0, 0, 0);
            acc[1][nt] = __builtin_amdgcn_mfma_f32_16x16x32_bf16(a1, b, acc[1][nt], 0, 0, 0);
        }
    }
    __syncthreads();

    float* outf = (float*)lds;
    #pragma unroll
    for (int mt = 0; mt < 2; ++mt)
        #pragma unroll
        for (int nt = 0; nt < 4; ++nt)
            #pragma unroll
            for (int r = 0; r < 4; ++r) {
                int row = mt * 16 + lg * 4 + r;
                int col = wave * 64 + nt * 16 + l15;
                outf[row * 256 + col] = acc[mt][nt][r];
            }
    __syncthreads();

    float4 c2v = *(const float4*)(g_c2 + lane * 4);
    float4 c3v = *(const float4*)(g_c3 + lane * 4);
    for (int r = 0; r < 8; ++r) {
        int row = wave * 8 + r;
        int t = base + row;
        if (t >= total) break;                   // wave-uniform
        float sd = Sdeg[row];
        float4 v = *(float4*)(outf + row * 256 + lane * 4);
        v.x += sd * c2v.x + c3v.x;
        v.y += sd * c2v.y + c3v.y;
        v.z += sd * c2v.z + c3v.z;
        v.w += sd * c2v.w + c3v.w;
        float ss = v.x * v.x + v.y * v.y + v.z * v.z + v.w * v.w;
        #pragma unroll
        for (int s = 32; s; s >>= 1) ss += __shfl_xor(ss, s);
        float inv = 1.0f / fmaxf(sqrtf(ss), 1e-12f);
        v.x *= inv; v.y *= inv; v.z *= inv; v.w *= inv;
        *(float4*)(out + (size_t)t * FDIM + lane * 4) = v;
    }
}

extern "C" void kernel_launch(void* const* d_in, const int* in_sizes, int n_in,
                              void* d_out, int out_size, void* d_ws, size_t ws_size,
                              hipStream_t stream) {
    const float* feat_data = (const float*)d_in[0];
    const float* feats     = (const float*)d_in[1];
    const float* W1        = (const float*)d_in[2];
    const float* b1        = (const float*)d_in[3];
    const float* W2        = (const float*)d_in[4];
    const float* b2        = (const float*)d_in[5];
    const int*   adj       = (const int*)d_in[6];
    const int*   in1       = (const int*)d_in[7];
    const int*   in2       = (const int*)d_in[8];
    const int*   neg       = (const int*)d_in[9];

    int B1 = in_sizes[7];
    int B2 = in_sizes[8];
    int Bn = in_sizes[9];
    int N  = in_sizes[0] / FDIM;
    int D  = in_sizes[6] / N;   // == 32

    float* out = (float*)d_out;
    int total = B1 + B2 + Bn;

    // ws layout (256B-aligned): [tab bf16 N*256][X bf16 total*512][deg f32 N][Sdeg f32 total]
    size_t off = 0;
    auto take = [&](size_t bytes) { size_t o = off; off = (off + bytes + 255) & ~(size_t)255; return o; };
    size_t tab_o  = take((size_t)N * FDIM * 2);
    size_t x_o    = take((size_t)total * K2 * 2);
    size_t deg_o  = take((size_t)N * 4);
    size_t sdeg_o = take((size_t)total * 4);
    bool usews = (ws_size >= off);

    char* wsb = (char*)d_ws;
    unsigned short* tab = usews ? (unsigned short*)(wsb + tab_o) : nullptr;
    unsigned short* X   = usews ? (unsigned short*)(wsb + x_o)   : nullptr;
    float* deg  = usews ? (float*)(wsb + deg_o)  : nullptr;
    float* Sdeg = usews ? (float*)(wsb + sdeg_o) : nullptr;

    build<<<1024, 256, 0, stream>>>(feat_data, feats, tab, deg, N);
    prep_w<<<FDIM, 256, 0, stream>>>(W1, W2, b1, b2, (float)D);
    gather<<<(total + 3) / 4, 256, 0, stream>>>(tab, deg, adj, in1, B1, in2, B2,
                                                neg, total, X, Sdeg);
    gemm_norm<<<(total + TM - 1) / TM, 256, 0, stream>>>(X, Sdeg, out, total);
}

// Round 9
// 112.425 us; speedup vs baseline: 1.1014x; 1.0015x over previous
//
#include <hip/hip_runtime.h>
#include <hip/hip_bf16.h>

#define FDIM 256
#define K2   512
#define DNB  32
#define TM   32
#define NMAX 100000
#define TMAX 20480

typedef __attribute__((ext_vector_type(8))) short bf16x8;
typedef __attribute__((ext_vector_type(8))) unsigned short u16x8;
typedef __attribute__((ext_vector_type(4))) float f32x4;

// Fallback scratch in BSS (used only if ws_size is too small).
__device__ __align__(16) unsigned short g_FDb[(size_t)NMAX * FDIM];
__device__ __align__(16) unsigned short g_Xb[(size_t)TMAX * K2];
__device__ float g_degb[NMAX];
__device__ float g_Sdegb[TMAX];
// Small combined-weight arrays stay in BSS (256 KB total, read-heavy).
__device__ __align__(16) unsigned short g_Wc[FDIM * K2];   // [o][k] bf16
__device__ float g_c2[FDIM];
__device__ float g_c3[FDIM];

__device__ __forceinline__ unsigned short f2bf(float f) {
    __hip_bfloat16 h = __float2bfloat16(f);
    return *reinterpret_cast<unsigned short*>(&h);
}
__device__ __forceinline__ float bf2f(unsigned short u) {
    return __uint_as_float(((unsigned)u) << 16);
}

// ---------- 1) build16: PURE fp32 -> bf16 stream, 32B in / 16B out per step ----------
__global__ __launch_bounds__(256) void build16(const float* __restrict__ fd,
                                               unsigned short* tab_p, int N) {
    unsigned short* tab = tab_p ? tab_p : g_FDb;

    size_t tidg = (size_t)blockIdx.x * 256 + threadIdx.x;
    size_t nthr = (size_t)gridDim.x * 256;
    size_t total8 = (size_t)N * (FDIM / 8);      // # 8-element groups
    const float4* in4 = (const float4*)fd;
    u16x8* out8 = (u16x8*)tab;

    size_t i = tidg;
    for (; i + 3 * nthr < total8; i += 4 * nthr) {
        float4 a[4], b[4];
        #pragma unroll
        for (int j = 0; j < 4; ++j) {
            size_t g = i + (size_t)j * nthr;
            a[j] = in4[2 * g];
            b[j] = in4[2 * g + 1];
        }
        #pragma unroll
        for (int j = 0; j < 4; ++j) {
            size_t g = i + (size_t)j * nthr;
            u16x8 o;
            o[0] = f2bf(a[j].x); o[1] = f2bf(a[j].y);
            o[2] = f2bf(a[j].z); o[3] = f2bf(a[j].w);
            o[4] = f2bf(b[j].x); o[5] = f2bf(b[j].y);
            o[6] = f2bf(b[j].z); o[7] = f2bf(b[j].w);
            out8[g] = o;
        }
    }
    for (; i < total8; i += nthr) {
        float4 a = in4[2 * i], b = in4[2 * i + 1];
        u16x8 o;
        o[0] = f2bf(a.x); o[1] = f2bf(a.y); o[2] = f2bf(a.z); o[3] = f2bf(a.w);
        o[4] = f2bf(b.x); o[5] = f2bf(b.y); o[6] = f2bf(b.z); o[7] = f2bf(b.w);
        out8[i] = o;
    }
}

// ---------- 2) prep_w: combined weights + degree table ----------
__global__ __launch_bounds__(256) void prep_w(const float* __restrict__ W1,
                                              const float* __restrict__ W2,
                                              const float* __restrict__ b1,
                                              const float* __restrict__ b2,
                                              const float* __restrict__ feats,
                                              float* deg_p,
                                              float Dmul, int N) {
    float* deg = deg_p ? deg_p : g_degb;
    __shared__ float w2s[FDIM];
    __shared__ float rv[4], ru[4];
    int o = blockIdx.x, tid = threadIdx.x;

    // degree table: 65536 threads grid-stride over N (scattered 4B, 1KB stride)
    for (size_t n = (size_t)o * 256 + tid; n < (size_t)N; n += 65536)
        deg[n] = feats[n * FDIM];

    w2s[tid] = W2[(size_t)o * K2 + FDIM + tid];
    __syncthreads();

    const float* w1a = W1 + tid;           // column k0 = tid       -> C1
    const float* w1b = W1 + FDIM + tid;    // column k1 = 256+tid   -> c2 sum
    float acc0 = 0.f, acc1 = 0.f;
    for (int j = 0; j < FDIM; j += 8) {
        float r0[8], r1[8];
        #pragma unroll
        for (int u = 0; u < 8; ++u) {
            r0[u] = w1a[(size_t)(j + u) * K2];
            r1[u] = w1b[(size_t)(j + u) * K2];
        }
        #pragma unroll
        for (int u = 0; u < 8; ++u) {
            acc0 = fmaf(w2s[j + u], r0[u], acc0);
            acc1 = fmaf(w2s[j + u], r1[u], acc1);
        }
    }
    g_Wc[(size_t)o * K2 + FDIM + tid] = f2bf(acc0);
    g_Wc[(size_t)o * K2 + tid]        = f2bf(W2[(size_t)o * K2 + tid]);

    float v = acc1;
    float u = b1[tid] * w2s[tid];
    #pragma unroll
    for (int s = 32; s; s >>= 1) { v += __shfl_down(v, s); u += __shfl_down(u, s); }
    if ((tid & 63) == 0) { rv[tid >> 6] = v; ru[tid >> 6] = u; }
    __syncthreads();
    if (tid == 0) {
        g_c2[o] = rv[0] + rv[1] + rv[2] + rv[3];
        g_c3[o] = b2[o] + Dmul * (ru[0] + ru[1] + ru[2] + ru[3]);
    }
}

// ---------- 3) gather: bf16 table rows, 1 wave/node, 8 rows in flight ----------
__global__ __launch_bounds__(256, 6) void gather(
    const unsigned short* tab_p, const float* deg_p,
    const int* __restrict__ adj,
    const int* __restrict__ in1, int B1,
    const int* __restrict__ in2, int B2,
    const int* __restrict__ neg, int total,
    unsigned short* X_p, float* Sdeg_p)
{
    const unsigned short* tab = tab_p ? tab_p : g_FDb;
    const float* deg = deg_p ? deg_p : g_degb;
    unsigned short* X = X_p ? X_p : g_Xb;
    float* Sdeg = Sdeg_p ? Sdeg_p : g_Sdegb;

    int wave = threadIdx.x >> 6, lane = threadIdx.x & 63;
    int t = blockIdx.x * 4 + wave;
    if (t >= total) return;
    int node = (t < B1) ? in1[t] : ((t < B1 + B2) ? in2[t - B1] : neg[t - B1 - B2]);

    int idx = 0; float dg = 0.f;
    if (lane < DNB) {
        idx = adj[(size_t)node * DNB + lane];
        dg = deg[idx];
    }
    #pragma unroll
    for (int s = 16; s; s >>= 1) dg += __shfl_down(dg, s);
    if (lane == 0) Sdeg[t] = dg;

    // node row passthrough (bf16): 8B/lane = full 512B row per wave-load
    ushort4 nf = *(const ushort4*)(tab + (size_t)node * FDIM + lane * 4);
    *(ushort4*)(X + (size_t)t * K2 + lane * 4) = nf;

    float a0 = 0.f, a1 = 0.f, a2 = 0.f, a3 = 0.f;
    #pragma unroll
    for (int d = 0; d < DNB; d += 8) {
        ushort4 v[8];
        #pragma unroll
        for (int u = 0; u < 8; ++u) {
            int nb = __shfl(idx, d + u);
            v[u] = *(const ushort4*)(tab + (size_t)nb * FDIM + lane * 4);
        }
        #pragma unroll
        for (int u = 0; u < 8; ++u) {
            a0 += bf2f(v[u].x);
            a1 += bf2f(v[u].y);
            a2 += bf2f(v[u].z);
            a3 += bf2f(v[u].w);
        }
    }
    *(ushort4*)(X + (size_t)t * K2 + FDIM + lane * 4) =
        make_ushort4(f2bf(a0), f2bf(a1), f2bf(a2), f2bf(a3));
}

// ---------- 4) GEMM (MFMA) + degree term + L2 normalize ----------
__global__ __launch_bounds__(256, 4) void gemm_norm(const unsigned short* X_p,
                                                    const float* Sdeg_p,
                                                    float* __restrict__ out, int total)
{
    const unsigned short* X = X_p ? X_p : g_Xb;
    const float* SdegG = Sdeg_p ? Sdeg_p : g_Sdegb;

    __shared__ __align__(16) char lds[TM * 1024];  // bf16 [32][512]; reused f32 [32][256]
    __shared__ float Sdeg[TM];

    int tid = threadIdx.x, wave = tid >> 6, lane = tid & 63;
    int base = blockIdx.x * TM;

    if (tid < TM) {
        int t = base + tid;
        Sdeg[tid] = (t < total) ? SdegG[t] : 0.f;
    }
    #pragma unroll
    for (int i = 0; i < 8; ++i) {
        int row = wave * 8 + i;
        int t = base + row;
        bf16x8 v = {0, 0, 0, 0, 0, 0, 0, 0};
        if (t < total) v = *(const bf16x8*)(X + (size_t)t * K2 + lane * 8);
        *(bf16x8*)(lds + row * 1024 + ((lane * 16) ^ ((row & 7) << 4))) = v;
    }
    __syncthreads();

    int l15 = lane & 15, lg = lane >> 4;
    int swzA = (l15 & 7) << 4;
    f32x4 acc[2][4];
    #pragma unroll
    for (int mt = 0; mt < 2; ++mt)
        #pragma unroll
        for (int nt = 0; nt < 4; ++nt) acc[mt][nt] = (f32x4){0.f, 0.f, 0.f, 0.f};

    const char* pA0 = lds + (size_t)l15 * 1024;
    const char* pA1 = lds + (size_t)(16 + l15) * 1024;
    const unsigned short* wcB = g_Wc + (size_t)(wave * 64 + l15) * K2 + lg * 8;

    #pragma unroll 4
    for (int kk = 0; kk < K2; kk += 32) {
        int kb = kk * 2 + lg * 16;
        bf16x8 a0 = *(const bf16x8*)(pA0 + (kb ^ swzA));
        bf16x8 a1 = *(const bf16x8*)(pA1 + (kb ^ swzA));
        #pragma unroll
        for (int nt = 0; nt < 4; ++nt) {
            bf16x8 b = *(const bf16x8*)(wcB + (size_t)nt * 16 * K2 + kk);
            acc[0][nt] = __builtin_amdgcn_mfma_f32_16x16x32_bf16(a0, b, acc[0][nt], 0, 0, 0);
            acc[1][nt] = __builtin_amdgcn_mfma_f32_16x16x32_bf16(a1, b, acc[1][nt], 0, 0, 0);
        }
    }
    __syncthreads();

    float* outf = (float*)lds;
    #pragma unroll
    for (int mt = 0; mt < 2; ++mt)
        #pragma unroll
        for (int nt = 0; nt < 4; ++nt)
            #pragma unroll
            for (int r = 0; r < 4; ++r) {
                int row = mt * 16 + lg * 4 + r;
                int col = wave * 64 + nt * 16 + l15;
                outf[row * 256 + col] = acc[mt][nt][r];
            }
    __syncthreads();

    float4 c2v = *(const float4*)(g_c2 + lane * 4);
    float4 c3v = *(const float4*)(g_c3 + lane * 4);
    for (int r = 0; r < 8; ++r) {
        int row = wave * 8 + r;
        int t = base + row;
        if (t >= total) break;                   // wave-uniform
        float sd = Sdeg[row];
        float4 v = *(float4*)(outf + row * 256 + lane * 4);
        v.x += sd * c2v.x + c3v.x;
        v.y += sd * c2v.y + c3v.y;
        v.z += sd * c2v.z + c3v.z;
        v.w += sd * c2v.w + c3v.w;
        float ss = v.x * v.x + v.y * v.y + v.z * v.z + v.w * v.w;
        #pragma unroll
        for (int s = 32; s; s >>= 1) ss += __shfl_xor(ss, s);
        float inv = 1.0f / fmaxf(sqrtf(ss), 1e-12f);
        v.x *= inv; v.y *= inv; v.z *= inv; v.w *= inv;
        *(float4*)(out + (size_t)t * FDIM + lane * 4) = v;
    }
}

extern "C" void kernel_launch(void* const* d_in, const int* in_sizes, int n_in,
                              void* d_out, int out_size, void* d_ws, size_t ws_size,
                              hipStream_t stream) {
    const float* feat_data = (const float*)d_in[0];
    const float* feats     = (const float*)d_in[1];
    const float* W1        = (const float*)d_in[2];
    const float* b1        = (const float*)d_in[3];
    const float* W2        = (const float*)d_in[4];
    const float* b2        = (const float*)d_in[5];
    const int*   adj       = (const int*)d_in[6];
    const int*   in1       = (const int*)d_in[7];
    const int*   in2       = (const int*)d_in[8];
    const int*   neg       = (const int*)d_in[9];

    int B1 = in_sizes[7];
    int B2 = in_sizes[8];
    int Bn = in_sizes[9];
    int N  = in_sizes[0] / FDIM;
    int D  = in_sizes[6] / N;   // == 32

    float* out = (float*)d_out;
    int total = B1 + B2 + Bn;

    // ws layout (256B-aligned): [tab bf16 N*256][X bf16 total*512][deg f32 N][Sdeg f32 total]
    size_t off = 0;
    auto take = [&](size_t bytes) { size_t o = off; off = (off + bytes + 255) & ~(size_t)255; return o; };
    size_t tab_o  = take((size_t)N * FDIM * 2);
    size_t x_o    = take((size_t)total * K2 * 2);
    size_t deg_o  = take((size_t)N * 4);
    size_t sdeg_o = take((size_t)total * 4);
    bool usews = (ws_size >= off);

    char* wsb = (char*)d_ws;
    unsigned short* tab = usews ? (unsigned short*)(wsb + tab_o) : nullptr;
    unsigned short* X   = usews ? (unsigned short*)(wsb + x_o)   : nullptr;
    float* deg  = usews ? (float*)(wsb + deg_o)  : nullptr;
    float* Sdeg = usews ? (float*)(wsb + sdeg_o) : nullptr;

    build16<<<2048, 256, 0, stream>>>(feat_data, tab, N);
    prep_w<<<FDIM, 256, 0, stream>>>(W1, W2, b1, b2, feats, deg, (float)D, N);
    gather<<<(total + 3) / 4, 256, 0, stream>>>(tab, deg, adj, in1, B1, in2, B2,
                                                neg, total, X, Sdeg);
    gemm_norm<<<(total + TM - 1) / TM, 256, 0, stream>>>(X, Sdeg, out, total);
}